// Round 11
// baseline (247.335 us; speedup 1.0000x reference)
//
#include <hip/hip_runtime.h>

#define G 32
#define NCELL (G * G * G)       // 32768
#define C_IN 3
#define C_OUT 64
#define PBLK 64                 // chunks per vtype; grid = 4*PBLK = 256 blocks
#define HTHREADS 1024

typedef float     f32x4  __attribute__((ext_vector_type(4)));
typedef int       i32x4  __attribute__((ext_vector_type(4)));
typedef _Float16  f16x4v __attribute__((ext_vector_type(4)));
typedef _Float16  f16x8v __attribute__((ext_vector_type(8)));

// ws layout (floats):
//   sums[NCELL*3] | cnt[NCELL] | avg[NCELL*3] | convout_f32[NCELL*64]
//   | tabA (half, NCELL*32 = NCELL*16 floats) | tabB (same)
//   | cellid[n] (int) | partial[4][PBLK][NCELL]

// ---------------- cellid precompute: coords read ONCE ----------------
__global__ void cellid_kernel(const i32x4* __restrict__ coords4,
                              int* __restrict__ cellid, int n) {
    int t = blockIdx.x * blockDim.x + threadIdx.x;   // one thread = 4 points
    int base = t * 4;
    if (base >= n) return;
    i32x4 a = coords4[t * 3 + 0];
    i32x4 b = coords4[t * 3 + 1];
    i32x4 c = coords4[t * 3 + 2];
    int c0 = (((a.x >> 4) * G + (a.y >> 4)) * G + (a.z >> 4));
    int c1 = (((a.w >> 4) * G + (b.x >> 4)) * G + (b.y >> 4));
    int c2 = (((b.z >> 4) * G + (b.w >> 4)) * G + (c.x >> 4));
    int c3 = (((c.y >> 4) * G + (c.z >> 4)) * G + (c.w >> 4));
    if (base + 3 < n) {
        i32x4 r = {c0, c1, c2, c3};
        *(i32x4*)&cellid[base] = r;
    } else {
        cellid[base] = c0;
        if (base + 1 < n) cellid[base + 1] = c1;
        if (base + 2 < n) cellid[base + 2] = c2;
    }
}

// ---------------- vtype-split LDS histogram (256 blocks, 1/CU) --------
__global__ __launch_bounds__(HTHREADS) void histo_kernel(
    const int* __restrict__ cellid,
    const float* __restrict__ feats,
    float* __restrict__ partial,   // [4][PBLK][NCELL]
    int n, int ppc) {
    __shared__ __align__(16) float h[NCELL];   // 128 KB
    int vtype = blockIdx.x & 3;
    int chunk = blockIdx.x >> 2;

    f32x4* h4 = (f32x4*)h;
    for (int t = threadIdx.x; t < NCELL / 4; t += HTHREADS)
        h4[t] = (f32x4){0.f, 0.f, 0.f, 0.f};
    __syncthreads();

    int start = chunk * ppc;
    int end = start + ppc; if (end > n) end = n;
    if (vtype < 3) {
        for (int i = start + threadIdx.x; i < end; i += HTHREADS) {
            int c = cellid[i];
            atomicAdd(&h[c], feats[i * 3 + vtype]);
        }
    } else {
        for (int i = start + threadIdx.x; i < end; i += HTHREADS) {
            int c = cellid[i];
            atomicAdd(&h[c], 1.0f);
        }
    }
    __syncthreads();

    f32x4* pp = (f32x4*)(partial + ((size_t)vtype * PBLK + chunk) * NCELL);
    for (int t = threadIdx.x; t < NCELL / 4; t += HTHREADS)
        pp[t] = h4[t];
}

// ---------------- reduce partials -> per-cell average ----------------
__global__ void reduce_kernel(const float* __restrict__ partial,
                              float* __restrict__ avg) {
    int cell = blockIdx.x * blockDim.x + threadIdx.x;
    if (cell >= NCELL) return;
    float s0 = 0.f, s1 = 0.f, s2 = 0.f, c = 0.f;
    for (int p = 0; p < PBLK; ++p) {
        s0 += partial[((size_t)0 * PBLK + p) * NCELL + cell];
        s1 += partial[((size_t)1 * PBLK + p) * NCELL + cell];
        s2 += partial[((size_t)2 * PBLK + p) * NCELL + cell];
        c  += partial[((size_t)3 * PBLK + p) * NCELL + cell];
    }
    float inv = c > 0.f ? 1.0f / c : 0.f;
    avg[cell * 3 + 0] = s0 * inv;
    avg[cell * 3 + 1] = s1 * inv;
    avg[cell * 3 + 2] = s2 * inv;
}

// ------ dense 3^3 conv -> TWO 2 MB fp16 half-tables (L2-resident) -----
__global__ void conv_half_kernel(const float* __restrict__ avg,
                                 const float* __restrict__ W,  // [64][3][27]
                                 _Float16* __restrict__ tabA,
                                 _Float16* __restrict__ tabB) {
    __shared__ float wlds[C_OUT * C_IN * 27];
    for (int t = threadIdx.x; t < C_OUT * C_IN * 27; t += blockDim.x)
        wlds[t] = W[t];
    __syncthreads();

    int cell = blockIdx.x * blockDim.x + threadIdx.x;
    if (cell >= NCELL) return;
    int z = cell & 31;
    int y = (cell >> 5) & 31;
    int x = cell >> 10;

    float acc[C_OUT];
#pragma unroll
    for (int c = 0; c < C_OUT; ++c) acc[c] = 0.f;

    for (int kd = 0; kd < 3; ++kd) {
        int nx = x + kd - 1;
        if (nx < 0 || nx >= G) continue;
        for (int kh = 0; kh < 3; ++kh) {
            int ny = y + kh - 1;
            if (ny < 0 || ny >= G) continue;
            for (int kw = 0; kw < 3; ++kw) {
                int nz = z + kw - 1;
                if (nz < 0 || nz >= G) continue;
                int nc = (nx * G + ny) * G + nz;
                float g0 = avg[nc * 3 + 0];   // empty cells are exactly 0
                float g1 = avg[nc * 3 + 1];
                float g2 = avg[nc * 3 + 2];
                int koff = (kd * 3 + kh) * 3 + kw;
#pragma unroll
                for (int co = 0; co < C_OUT; ++co) {
                    const float* wp = &wlds[co * C_IN * 27 + koff];
                    acc[co] += wp[0] * g0 + wp[27] * g1 + wp[54] * g2;
                }
            }
        }
    }
    f16x8v* dstA = (f16x8v*)&tabA[(size_t)cell * 32];
    f16x8v* dstB = (f16x8v*)&tabB[(size_t)cell * 32];
#pragma unroll
    for (int q = 0; q < 4; ++q) {
        f16x8v pa, pb;
#pragma unroll
        for (int e = 0; e < 8; ++e) {
            pa[e] = (_Float16)acc[q * 8 + e];
            pb[e] = (_Float16)acc[32 + q * 8 + e];
        }
        dstA[q] = pa;
        dstB[q] = pb;
    }
}

// -- gather one channel-half: 4 thr/point, 2 indep loads + 2 NT stores --
// Thread handles f32x4 slots c2 and c2+4 of its half-row. Store instr 1
// (slots 0-3) covers bytes [0,64) of each point's half-row across the
// 4-lane group; store instr 2 covers [64,128) -- full 64-B granules.
__global__ void gather_half2_kernel(const int* __restrict__ cellid,
                                    const f16x4v* __restrict__ tabhalf,
                                    f32x4* __restrict__ out, int n, int halfoff) {
    long g = (long)blockIdx.x * blockDim.x + threadIdx.x;
    int i = (int)(g >> 2);
    int c2 = (int)(g & 3);
    if (i >= n) return;
    int cell = cellid[i];                            // cached, shared by 4 lanes
    f16x4v v0 = tabhalf[(size_t)cell * 8 + c2];      // 2 MB working set -> L2 hit
    f16x4v v1 = tabhalf[(size_t)cell * 8 + 4 + c2];  // independent second chain
    f32x4 o0 = {(float)v0[0], (float)v0[1], (float)v0[2], (float)v0[3]};
    f32x4 o1 = {(float)v1[0], (float)v1[1], (float)v1[2], (float)v1[3]};
    __builtin_nontemporal_store(o0, &out[(size_t)i * 16 + halfoff + c2]);
    __builtin_nontemporal_store(o1, &out[(size_t)i * 16 + halfoff + c2 + 4]);
}

// ---------------- fallback path (tiny ws), all f32 ----------------
__global__ void scatter_atomic_kernel(const int* __restrict__ coords,
                                      const float* __restrict__ feats,
                                      float* __restrict__ sums,
                                      float* __restrict__ cnt, int n) {
    int i = blockIdx.x * blockDim.x + threadIdx.x;
    if (i >= n) return;
    int x = coords[i * 3 + 0] >> 4;
    int y = coords[i * 3 + 1] >> 4;
    int z = coords[i * 3 + 2] >> 4;
    int cell = (x * G + y) * G + z;
    atomicAdd(&sums[cell * 3 + 0], feats[i * 3 + 0]);
    atomicAdd(&sums[cell * 3 + 1], feats[i * 3 + 1]);
    atomicAdd(&sums[cell * 3 + 2], feats[i * 3 + 2]);
    atomicAdd(&cnt[cell], 1.0f);
}

__global__ void avg_kernel(const float* __restrict__ sums,
                           const float* __restrict__ cnt,
                           float* __restrict__ avg) {
    int cell = blockIdx.x * blockDim.x + threadIdx.x;
    if (cell >= NCELL) return;
    float c = cnt[cell];
    float inv = c > 0.f ? 1.0f / c : 0.f;
    avg[cell * 3 + 0] = sums[cell * 3 + 0] * inv;
    avg[cell * 3 + 1] = sums[cell * 3 + 1] * inv;
    avg[cell * 3 + 2] = sums[cell * 3 + 2] * inv;
}

__global__ void conv_kernel(const float* __restrict__ avg,
                            const float* __restrict__ W,
                            float* __restrict__ convout) {
    __shared__ float wlds[C_OUT * C_IN * 27];
    for (int t = threadIdx.x; t < C_OUT * C_IN * 27; t += blockDim.x)
        wlds[t] = W[t];
    __syncthreads();

    int cell = blockIdx.x * blockDim.x + threadIdx.x;
    if (cell >= NCELL) return;
    int z = cell & 31;
    int y = (cell >> 5) & 31;
    int x = cell >> 10;

    float acc[C_OUT];
#pragma unroll
    for (int c = 0; c < C_OUT; ++c) acc[c] = 0.f;

    for (int kd = 0; kd < 3; ++kd) {
        int nx = x + kd - 1;
        if (nx < 0 || nx >= G) continue;
        for (int kh = 0; kh < 3; ++kh) {
            int ny = y + kh - 1;
            if (ny < 0 || ny >= G) continue;
            for (int kw = 0; kw < 3; ++kw) {
                int nz = z + kw - 1;
                if (nz < 0 || nz >= G) continue;
                int nc = (nx * G + ny) * G + nz;
                float g0 = avg[nc * 3 + 0];
                float g1 = avg[nc * 3 + 1];
                float g2 = avg[nc * 3 + 2];
                int koff = (kd * 3 + kh) * 3 + kw;
#pragma unroll
                for (int co = 0; co < C_OUT; ++co) {
                    const float* wp = &wlds[co * C_IN * 27 + koff];
                    acc[co] += wp[0] * g0 + wp[27] * g1 + wp[54] * g2;
                }
            }
        }
    }
    float* op = &convout[(size_t)cell * C_OUT];
#pragma unroll
    for (int co = 0; co < C_OUT; ++co) op[co] = acc[co];
}

__global__ void gather_coords_kernel(const int* __restrict__ coords,
                                     const f32x4* __restrict__ convout,
                                     f32x4* __restrict__ out, int n) {
    long g = (long)blockIdx.x * blockDim.x + threadIdx.x;
    int i = (int)(g >> 4);
    int c4 = (int)(g & 15);
    if (i >= n) return;
    int x = coords[i * 3 + 0] >> 4;
    int y = coords[i * 3 + 1] >> 4;
    int z = coords[i * 3 + 2] >> 4;
    int cell = (x * G + y) * G + z;
    out[(size_t)i * 16 + c4] = convout[(size_t)cell * 16 + c4];
}

extern "C" void kernel_launch(void* const* d_in, const int* in_sizes, int n_in,
                              void* d_out, int out_size, void* d_ws, size_t ws_size,
                              hipStream_t stream) {
    const int*   coords = (const int*)d_in[0];
    const float* feats  = (const float*)d_in[1];
    const float* W      = (const float*)d_in[2];
    float* out = (float*)d_out;
    int n = in_sizes[0] / 3;   // 2,000,000

    float*    sums    = (float*)d_ws;
    float*    cnt     = sums + NCELL * 3;
    float*    avg     = cnt + NCELL;
    float*    convout = avg + NCELL * 3;                       // f32 table (fallback)
    _Float16* tabA    = (_Float16*)(convout + (size_t)NCELL * 64);
    _Float16* tabB    = tabA + (size_t)NCELL * 32;
    int*      cellid  = (int*)((float*)tabA + (size_t)NCELL * 32);
    float*    partial = (float*)(cellid + ((n + 3) & ~3));

    size_t need = ((size_t)NCELL * (3 + 1 + 3 + 64 + 32) + ((n + 3) & ~3) +
                   (size_t)4 * PBLK * NCELL) * 4;
    bool fast = (ws_size >= need);

    if (fast) {
        int npt4 = (n + 3) / 4;
        cellid_kernel<<<(npt4 + 255) / 256, 256, 0, stream>>>(
            (const i32x4*)coords, cellid, n);
        int ppc = (n + PBLK - 1) / PBLK;
        histo_kernel<<<4 * PBLK, HTHREADS, 0, stream>>>(cellid, feats, partial, n, ppc);
        reduce_kernel<<<NCELL / 256, 256, 0, stream>>>(partial, avg);
        conv_half_kernel<<<NCELL / 256, 256, 0, stream>>>(avg, W, tabA, tabB);
        long ghalf = (long)n * 4;
        gather_half2_kernel<<<(int)((ghalf + 255) / 256), 256, 0, stream>>>(
            cellid, (const f16x4v*)tabA, (f32x4*)out, n, 0);
        gather_half2_kernel<<<(int)((ghalf + 255) / 256), 256, 0, stream>>>(
            cellid, (const f16x4v*)tabB, (f32x4*)out, n, 8);
    } else {
        hipMemsetAsync(d_ws, 0, NCELL * 4 * sizeof(float), stream);
        scatter_atomic_kernel<<<(n + 255) / 256, 256, 0, stream>>>(coords, feats, sums, cnt, n);
        avg_kernel<<<NCELL / 256, 256, 0, stream>>>(sums, cnt, avg);
        conv_kernel<<<NCELL / 256, 256, 0, stream>>>(avg, W, convout);
        long total = (long)n * 16;
        gather_coords_kernel<<<(int)((total + 255) / 256), 256, 0, stream>>>(
            coords, (const f32x4*)convout, (f32x4*)out, n);
    }
}

// Round 12
// 194.335 us; speedup vs baseline: 1.2727x; 1.2727x over previous
//
#include <hip/hip_runtime.h>

#define G 32
#define NCELL (G * G * G)       // 32768
#define C_IN 3
#define C_OUT 64
#define PBLK 64                 // chunks per vtype; grid = 4*PBLK = 256 blocks
#define HTHREADS 1024

typedef float          f32x4  __attribute__((ext_vector_type(4)));
typedef int            i32x4  __attribute__((ext_vector_type(4)));
typedef unsigned short u16x4  __attribute__((ext_vector_type(4)));
typedef _Float16       f16x4v __attribute__((ext_vector_type(4)));
typedef _Float16       f16x8v __attribute__((ext_vector_type(8)));

// ws layout (floats):
//   sums[NCELL*3] | cnt[NCELL] | avg[NCELL*3] | convout_f32[NCELL*64]
//   | tabA (half, NCELL*32) | tabB (half, NCELL*32)
//   | cellid[n] (u16) | partial[4][PBLK][NCELL]

// ---------------- cellid precompute: coords read ONCE, u16 out --------
__global__ void cellid_kernel(const i32x4* __restrict__ coords4,
                              unsigned short* __restrict__ cellid, int n) {
    int t = blockIdx.x * blockDim.x + threadIdx.x;   // one thread = 4 points
    int base = t * 4;
    if (base >= n) return;
    i32x4 a = coords4[t * 3 + 0];
    i32x4 b = coords4[t * 3 + 1];
    i32x4 c = coords4[t * 3 + 2];
    int c0 = (((a.x >> 4) * G + (a.y >> 4)) * G + (a.z >> 4));
    int c1 = (((a.w >> 4) * G + (b.x >> 4)) * G + (b.y >> 4));
    int c2 = (((b.z >> 4) * G + (b.w >> 4)) * G + (c.x >> 4));
    int c3 = (((c.y >> 4) * G + (c.z >> 4)) * G + (c.w >> 4));
    if (base + 3 < n) {
        u16x4 r = {(unsigned short)c0, (unsigned short)c1,
                   (unsigned short)c2, (unsigned short)c3};
        *(u16x4*)&cellid[base] = r;
    } else {
        cellid[base] = (unsigned short)c0;
        if (base + 1 < n) cellid[base + 1] = (unsigned short)c1;
        if (base + 2 < n) cellid[base + 2] = (unsigned short)c2;
    }
}

// ---------------- vtype-split LDS histogram (256 blocks, 1/CU) --------
__global__ __launch_bounds__(HTHREADS) void histo_kernel(
    const unsigned short* __restrict__ cellid,
    const float* __restrict__ feats,
    float* __restrict__ partial,   // [4][PBLK][NCELL]
    int n, int ppc) {
    __shared__ __align__(16) float h[NCELL];   // 128 KB
    int vtype = blockIdx.x & 3;
    int chunk = blockIdx.x >> 2;

    f32x4* h4 = (f32x4*)h;
    for (int t = threadIdx.x; t < NCELL / 4; t += HTHREADS)
        h4[t] = (f32x4){0.f, 0.f, 0.f, 0.f};
    __syncthreads();

    int start = chunk * ppc;
    int end = start + ppc; if (end > n) end = n;
    if (vtype < 3) {
        for (int i = start + threadIdx.x; i < end; i += HTHREADS) {
            int c = cellid[i];
            atomicAdd(&h[c], feats[i * 3 + vtype]);
        }
    } else {
        for (int i = start + threadIdx.x; i < end; i += HTHREADS) {
            int c = cellid[i];
            atomicAdd(&h[c], 1.0f);
        }
    }
    __syncthreads();

    f32x4* pp = (f32x4*)(partial + ((size_t)vtype * PBLK + chunk) * NCELL);
    for (int t = threadIdx.x; t < NCELL / 4; t += HTHREADS)
        pp[t] = h4[t];
}

// ---------------- reduce partials -> per-cell average ----------------
__global__ void reduce_kernel(const float* __restrict__ partial,
                              float* __restrict__ avg) {
    int cell = blockIdx.x * blockDim.x + threadIdx.x;
    if (cell >= NCELL) return;
    float s0 = 0.f, s1 = 0.f, s2 = 0.f, c = 0.f;
    for (int p = 0; p < PBLK; ++p) {
        s0 += partial[((size_t)0 * PBLK + p) * NCELL + cell];
        s1 += partial[((size_t)1 * PBLK + p) * NCELL + cell];
        s2 += partial[((size_t)2 * PBLK + p) * NCELL + cell];
        c  += partial[((size_t)3 * PBLK + p) * NCELL + cell];
    }
    float inv = c > 0.f ? 1.0f / c : 0.f;
    avg[cell * 3 + 0] = s0 * inv;
    avg[cell * 3 + 1] = s1 * inv;
    avg[cell * 3 + 2] = s2 * inv;
}

// ------ dense 3^3 conv -> TWO 2 MB fp16 half-tables (L2/L3 hot) -------
__global__ void conv_half_kernel(const float* __restrict__ avg,
                                 const float* __restrict__ W,  // [64][3][27]
                                 _Float16* __restrict__ tabA,
                                 _Float16* __restrict__ tabB) {
    __shared__ float wlds[C_OUT * C_IN * 27];
    for (int t = threadIdx.x; t < C_OUT * C_IN * 27; t += blockDim.x)
        wlds[t] = W[t];
    __syncthreads();

    int cell = blockIdx.x * blockDim.x + threadIdx.x;
    if (cell >= NCELL) return;
    int z = cell & 31;
    int y = (cell >> 5) & 31;
    int x = cell >> 10;

    float acc[C_OUT];
#pragma unroll
    for (int c = 0; c < C_OUT; ++c) acc[c] = 0.f;

    for (int kd = 0; kd < 3; ++kd) {
        int nx = x + kd - 1;
        if (nx < 0 || nx >= G) continue;
        for (int kh = 0; kh < 3; ++kh) {
            int ny = y + kh - 1;
            if (ny < 0 || ny >= G) continue;
            for (int kw = 0; kw < 3; ++kw) {
                int nz = z + kw - 1;
                if (nz < 0 || nz >= G) continue;
                int nc = (nx * G + ny) * G + nz;
                float g0 = avg[nc * 3 + 0];   // empty cells are exactly 0
                float g1 = avg[nc * 3 + 1];
                float g2 = avg[nc * 3 + 2];
                int koff = (kd * 3 + kh) * 3 + kw;
#pragma unroll
                for (int co = 0; co < C_OUT; ++co) {
                    const float* wp = &wlds[co * C_IN * 27 + koff];
                    acc[co] += wp[0] * g0 + wp[27] * g1 + wp[54] * g2;
                }
            }
        }
    }
    f16x8v* dstA = (f16x8v*)&tabA[(size_t)cell * 32];
    f16x8v* dstB = (f16x8v*)&tabB[(size_t)cell * 32];
#pragma unroll
    for (int q = 0; q < 4; ++q) {
        f16x8v pa, pb;
#pragma unroll
        for (int e = 0; e < 8; ++e) {
            pa[e] = (_Float16)acc[q * 8 + e];
            pb[e] = (_Float16)acc[32 + q * 8 + e];
        }
        dstA[q] = pa;
        dstB[q] = pb;
    }
}

// ---- gather one channel-half: 8 thr/point, NT store (R9 structure) ----
__global__ void gather_half2_kernel(const unsigned short* __restrict__ cellid,
                                    const f16x4v* __restrict__ tabhalf,
                                    f32x4* __restrict__ out, int n, int halfoff) {
    long g = (long)blockIdx.x * blockDim.x + threadIdx.x;
    int i = (int)(g >> 3);
    int c4 = (int)(g & 7);
    if (i >= n) return;
    int cell = cellid[i];                         // cached: 16 B/wave, shared
    f16x4v v = tabhalf[(size_t)cell * 8 + c4];    // 2 MB working set, hot
    f32x4 o = {(float)v[0], (float)v[1], (float)v[2], (float)v[3]};
    __builtin_nontemporal_store(o, &out[(size_t)i * 16 + halfoff + c4]);
}

// ---------------- fallback path (tiny ws), all f32 ----------------
__global__ void scatter_atomic_kernel(const int* __restrict__ coords,
                                      const float* __restrict__ feats,
                                      float* __restrict__ sums,
                                      float* __restrict__ cnt, int n) {
    int i = blockIdx.x * blockDim.x + threadIdx.x;
    if (i >= n) return;
    int x = coords[i * 3 + 0] >> 4;
    int y = coords[i * 3 + 1] >> 4;
    int z = coords[i * 3 + 2] >> 4;
    int cell = (x * G + y) * G + z;
    atomicAdd(&sums[cell * 3 + 0], feats[i * 3 + 0]);
    atomicAdd(&sums[cell * 3 + 1], feats[i * 3 + 1]);
    atomicAdd(&sums[cell * 3 + 2], feats[i * 3 + 2]);
    atomicAdd(&cnt[cell], 1.0f);
}

__global__ void avg_kernel(const float* __restrict__ sums,
                           const float* __restrict__ cnt,
                           float* __restrict__ avg) {
    int cell = blockIdx.x * blockDim.x + threadIdx.x;
    if (cell >= NCELL) return;
    float c = cnt[cell];
    float inv = c > 0.f ? 1.0f / c : 0.f;
    avg[cell * 3 + 0] = sums[cell * 3 + 0] * inv;
    avg[cell * 3 + 1] = sums[cell * 3 + 1] * inv;
    avg[cell * 3 + 2] = sums[cell * 3 + 2] * inv;
}

__global__ void conv_kernel(const float* __restrict__ avg,
                            const float* __restrict__ W,
                            float* __restrict__ convout) {
    __shared__ float wlds[C_OUT * C_IN * 27];
    for (int t = threadIdx.x; t < C_OUT * C_IN * 27; t += blockDim.x)
        wlds[t] = W[t];
    __syncthreads();

    int cell = blockIdx.x * blockDim.x + threadIdx.x;
    if (cell >= NCELL) return;
    int z = cell & 31;
    int y = (cell >> 5) & 31;
    int x = cell >> 10;

    float acc[C_OUT];
#pragma unroll
    for (int c = 0; c < C_OUT; ++c) acc[c] = 0.f;

    for (int kd = 0; kd < 3; ++kd) {
        int nx = x + kd - 1;
        if (nx < 0 || nx >= G) continue;
        for (int kh = 0; kh < 3; ++kh) {
            int ny = y + kh - 1;
            if (ny < 0 || ny >= G) continue;
            for (int kw = 0; kw < 3; ++kw) {
                int nz = z + kw - 1;
                if (nz < 0 || nz >= G) continue;
                int nc = (nx * G + ny) * G + nz;
                float g0 = avg[nc * 3 + 0];
                float g1 = avg[nc * 3 + 1];
                float g2 = avg[nc * 3 + 2];
                int koff = (kd * 3 + kh) * 3 + kw;
#pragma unroll
                for (int co = 0; co < C_OUT; ++co) {
                    const float* wp = &wlds[co * C_IN * 27 + koff];
                    acc[co] += wp[0] * g0 + wp[27] * g1 + wp[54] * g2;
                }
            }
        }
    }
    float* op = &convout[(size_t)cell * C_OUT];
#pragma unroll
    for (int co = 0; co < C_OUT; ++co) op[co] = acc[co];
}

__global__ void gather_coords_kernel(const int* __restrict__ coords,
                                     const f32x4* __restrict__ convout,
                                     f32x4* __restrict__ out, int n) {
    long g = (long)blockIdx.x * blockDim.x + threadIdx.x;
    int i = (int)(g >> 4);
    int c4 = (int)(g & 15);
    if (i >= n) return;
    int x = coords[i * 3 + 0] >> 4;
    int y = coords[i * 3 + 1] >> 4;
    int z = coords[i * 3 + 2] >> 4;
    int cell = (x * G + y) * G + z;
    out[(size_t)i * 16 + c4] = convout[(size_t)cell * 16 + c4];
}

extern "C" void kernel_launch(void* const* d_in, const int* in_sizes, int n_in,
                              void* d_out, int out_size, void* d_ws, size_t ws_size,
                              hipStream_t stream) {
    const int*   coords = (const int*)d_in[0];
    const float* feats  = (const float*)d_in[1];
    const float* W      = (const float*)d_in[2];
    float* out = (float*)d_out;
    int n = in_sizes[0] / 3;   // 2,000,000

    float*          sums    = (float*)d_ws;
    float*          cnt     = sums + NCELL * 3;
    float*          avg     = cnt + NCELL;
    float*          convout = avg + NCELL * 3;                 // f32 table (fallback)
    _Float16*       tabA    = (_Float16*)(convout + (size_t)NCELL * 64);
    _Float16*       tabB    = tabA + (size_t)NCELL * 32;
    unsigned short* cellid  = (unsigned short*)((float*)tabA + (size_t)NCELL * 32);
    size_t          cid_elems = ((size_t)n + 7) & ~(size_t)7;  // keep 16B align
    float*          partial = (float*)(cellid + cid_elems);

    size_t need = ((size_t)NCELL * (3 + 1 + 3 + 64 + 32) +
                   (size_t)4 * PBLK * NCELL) * 4 + cid_elems * 2;
    bool fast = (ws_size >= need);

    if (fast) {
        int npt4 = (n + 3) / 4;
        cellid_kernel<<<(npt4 + 255) / 256, 256, 0, stream>>>(
            (const i32x4*)coords, cellid, n);
        int ppc = (n + PBLK - 1) / PBLK;
        histo_kernel<<<4 * PBLK, HTHREADS, 0, stream>>>(cellid, feats, partial, n, ppc);
        reduce_kernel<<<NCELL / 256, 256, 0, stream>>>(partial, avg);
        conv_half_kernel<<<NCELL / 256, 256, 0, stream>>>(avg, W, tabA, tabB);
        long ghalf = (long)n * 8;
        gather_half2_kernel<<<(int)((ghalf + 255) / 256), 256, 0, stream>>>(
            cellid, (const f16x4v*)tabA, (f32x4*)out, n, 0);
        gather_half2_kernel<<<(int)((ghalf + 255) / 256), 256, 0, stream>>>(
            cellid, (const f16x4v*)tabB, (f32x4*)out, n, 8);
    } else {
        hipMemsetAsync(d_ws, 0, NCELL * 4 * sizeof(float), stream);
        scatter_atomic_kernel<<<(n + 255) / 256, 256, 0, stream>>>(coords, feats, sums, cnt, n);
        avg_kernel<<<NCELL / 256, 256, 0, stream>>>(sums, cnt, avg);
        conv_kernel<<<NCELL / 256, 256, 0, stream>>>(avg, W, convout);
        long total = (long)n * 16;
        gather_coords_kernel<<<(int)((total + 255) / 256), 256, 0, stream>>>(
            coords, (const f32x4*)convout, (f32x4*)out, n);
    }
}

// Round 13
// 192.782 us; speedup vs baseline: 1.2830x; 1.0081x over previous
//
#include <hip/hip_runtime.h>

#define G 32
#define NCELL (G * G * G)       // 32768
#define C_IN 3
#define C_OUT 64
#define PBLK 64                 // chunks per vtype; grid = 4*PBLK = 256 blocks
#define HTHREADS 1024

typedef float          f32x4  __attribute__((ext_vector_type(4)));
typedef int            i32x4  __attribute__((ext_vector_type(4)));
typedef unsigned short u16x4  __attribute__((ext_vector_type(4)));
typedef _Float16       f16x4v __attribute__((ext_vector_type(4)));
typedef _Float16       f16x8v __attribute__((ext_vector_type(8)));

// ws layout (floats):
//   sums[NCELL*3] | cnt[NCELL] | avg[NCELL*3] | convout_f32[NCELL*64]
//   | tabA (half, NCELL*32) | tabB (half, NCELL*32)
//   | cellid[n] (u16) | partial[4][PBLK][NCELL]

// ---------------- cellid precompute: coords read ONCE, u16 out --------
__global__ void cellid_kernel(const i32x4* __restrict__ coords4,
                              unsigned short* __restrict__ cellid, int n) {
    int t = blockIdx.x * blockDim.x + threadIdx.x;   // one thread = 4 points
    int base = t * 4;
    if (base >= n) return;
    i32x4 a = coords4[t * 3 + 0];
    i32x4 b = coords4[t * 3 + 1];
    i32x4 c = coords4[t * 3 + 2];
    int c0 = (((a.x >> 4) * G + (a.y >> 4)) * G + (a.z >> 4));
    int c1 = (((a.w >> 4) * G + (b.x >> 4)) * G + (b.y >> 4));
    int c2 = (((b.z >> 4) * G + (b.w >> 4)) * G + (c.x >> 4));
    int c3 = (((c.y >> 4) * G + (c.z >> 4)) * G + (c.w >> 4));
    if (base + 3 < n) {
        u16x4 r = {(unsigned short)c0, (unsigned short)c1,
                   (unsigned short)c2, (unsigned short)c3};
        *(u16x4*)&cellid[base] = r;
    } else {
        cellid[base] = (unsigned short)c0;
        if (base + 1 < n) cellid[base + 1] = (unsigned short)c1;
        if (base + 2 < n) cellid[base + 2] = (unsigned short)c2;
    }
}

// -------- vtype-split LDS histogram; same-chunk blocks share an XCD ----
// Default dispatch: XCD = blockIdx % 8 [m09]. Chunk c's four vtype blocks
// get bids ((c%8)*4+v)*8 + c/8 -- all == c/8 (mod 8) => same XCD, so the
// chunk's cellid/feats slice (~3.5 MB) is shared in that XCD's 4 MB L2.
__global__ __launch_bounds__(HTHREADS) void histo_kernel(
    const unsigned short* __restrict__ cellid,
    const float* __restrict__ feats,
    float* __restrict__ partial,   // [4][PBLK][NCELL]
    int n, int ppc) {
    __shared__ __align__(16) float h[NCELL];   // 128 KB
    int xcd = blockIdx.x & 7;          // residue mod 8 = XCD id
    int s   = blockIdx.x >> 3;         // 0..31 within this XCD
    int chunk = xcd * 8 + (s >> 2);    // 8 chunks per XCD
    int vtype = s & 3;

    f32x4* h4 = (f32x4*)h;
    for (int t = threadIdx.x; t < NCELL / 4; t += HTHREADS)
        h4[t] = (f32x4){0.f, 0.f, 0.f, 0.f};
    __syncthreads();

    int start = chunk * ppc;
    int end = start + ppc; if (end > n) end = n;
    if (vtype < 3) {
        for (int i = start + threadIdx.x; i < end; i += HTHREADS) {
            int c = cellid[i];
            atomicAdd(&h[c], feats[i * 3 + vtype]);
        }
    } else {
        for (int i = start + threadIdx.x; i < end; i += HTHREADS) {
            int c = cellid[i];
            atomicAdd(&h[c], 1.0f);
        }
    }
    __syncthreads();

    f32x4* pp = (f32x4*)(partial + ((size_t)vtype * PBLK + chunk) * NCELL);
    for (int t = threadIdx.x; t < NCELL / 4; t += HTHREADS)
        pp[t] = h4[t];
}

// ---------------- reduce partials -> per-cell average ----------------
__global__ void reduce_kernel(const float* __restrict__ partial,
                              float* __restrict__ avg) {
    int cell = blockIdx.x * blockDim.x + threadIdx.x;
    if (cell >= NCELL) return;
    float s0 = 0.f, s1 = 0.f, s2 = 0.f, c = 0.f;
    for (int p = 0; p < PBLK; ++p) {
        s0 += partial[((size_t)0 * PBLK + p) * NCELL + cell];
        s1 += partial[((size_t)1 * PBLK + p) * NCELL + cell];
        s2 += partial[((size_t)2 * PBLK + p) * NCELL + cell];
        c  += partial[((size_t)3 * PBLK + p) * NCELL + cell];
    }
    float inv = c > 0.f ? 1.0f / c : 0.f;
    avg[cell * 3 + 0] = s0 * inv;
    avg[cell * 3 + 1] = s1 * inv;
    avg[cell * 3 + 2] = s2 * inv;
}

// ------ dense 3^3 conv -> TWO 2 MB fp16 half-tables (L2/L3 hot) -------
__global__ void conv_half_kernel(const float* __restrict__ avg,
                                 const float* __restrict__ W,  // [64][3][27]
                                 _Float16* __restrict__ tabA,
                                 _Float16* __restrict__ tabB) {
    __shared__ float wlds[C_OUT * C_IN * 27];
    for (int t = threadIdx.x; t < C_OUT * C_IN * 27; t += blockDim.x)
        wlds[t] = W[t];
    __syncthreads();

    int cell = blockIdx.x * blockDim.x + threadIdx.x;
    if (cell >= NCELL) return;
    int z = cell & 31;
    int y = (cell >> 5) & 31;
    int x = cell >> 10;

    float acc[C_OUT];
#pragma unroll
    for (int c = 0; c < C_OUT; ++c) acc[c] = 0.f;

    for (int kd = 0; kd < 3; ++kd) {
        int nx = x + kd - 1;
        if (nx < 0 || nx >= G) continue;
        for (int kh = 0; kh < 3; ++kh) {
            int ny = y + kh - 1;
            if (ny < 0 || ny >= G) continue;
            for (int kw = 0; kw < 3; ++kw) {
                int nz = z + kw - 1;
                if (nz < 0 || nz >= G) continue;
                int nc = (nx * G + ny) * G + nz;
                float g0 = avg[nc * 3 + 0];   // empty cells are exactly 0
                float g1 = avg[nc * 3 + 1];
                float g2 = avg[nc * 3 + 2];
                int koff = (kd * 3 + kh) * 3 + kw;
#pragma unroll
                for (int co = 0; co < C_OUT; ++co) {
                    const float* wp = &wlds[co * C_IN * 27 + koff];
                    acc[co] += wp[0] * g0 + wp[27] * g1 + wp[54] * g2;
                }
            }
        }
    }
    f16x8v* dstA = (f16x8v*)&tabA[(size_t)cell * 32];
    f16x8v* dstB = (f16x8v*)&tabB[(size_t)cell * 32];
#pragma unroll
    for (int q = 0; q < 4; ++q) {
        f16x8v pa, pb;
#pragma unroll
        for (int e = 0; e < 8; ++e) {
            pa[e] = (_Float16)acc[q * 8 + e];
            pb[e] = (_Float16)acc[32 + q * 8 + e];
        }
        dstA[q] = pa;
        dstB[q] = pb;
    }
}

// ---- gather one channel-half: 8 thr/point, NT store (R9 structure) ----
__global__ void gather_half2_kernel(const unsigned short* __restrict__ cellid,
                                    const f16x4v* __restrict__ tabhalf,
                                    f32x4* __restrict__ out, int n, int halfoff) {
    long g = (long)blockIdx.x * blockDim.x + threadIdx.x;
    int i = (int)(g >> 3);
    int c4 = (int)(g & 7);
    if (i >= n) return;
    int cell = cellid[i];                         // cached: 16 B/wave, shared
    f16x4v v = tabhalf[(size_t)cell * 8 + c4];    // 2 MB working set, hot
    f32x4 o = {(float)v[0], (float)v[1], (float)v[2], (float)v[3]};
    __builtin_nontemporal_store(o, &out[(size_t)i * 16 + halfoff + c4]);
}

// ---------------- fallback path (tiny ws), all f32 ----------------
__global__ void scatter_atomic_kernel(const int* __restrict__ coords,
                                      const float* __restrict__ feats,
                                      float* __restrict__ sums,
                                      float* __restrict__ cnt, int n) {
    int i = blockIdx.x * blockDim.x + threadIdx.x;
    if (i >= n) return;
    int x = coords[i * 3 + 0] >> 4;
    int y = coords[i * 3 + 1] >> 4;
    int z = coords[i * 3 + 2] >> 4;
    int cell = (x * G + y) * G + z;
    atomicAdd(&sums[cell * 3 + 0], feats[i * 3 + 0]);
    atomicAdd(&sums[cell * 3 + 1], feats[i * 3 + 1]);
    atomicAdd(&sums[cell * 3 + 2], feats[i * 3 + 2]);
    atomicAdd(&cnt[cell], 1.0f);
}

__global__ void avg_kernel(const float* __restrict__ sums,
                           const float* __restrict__ cnt,
                           float* __restrict__ avg) {
    int cell = blockIdx.x * blockDim.x + threadIdx.x;
    if (cell >= NCELL) return;
    float c = cnt[cell];
    float inv = c > 0.f ? 1.0f / c : 0.f;
    avg[cell * 3 + 0] = sums[cell * 3 + 0] * inv;
    avg[cell * 3 + 1] = sums[cell * 3 + 1] * inv;
    avg[cell * 3 + 2] = sums[cell * 3 + 2] * inv;
}

__global__ void conv_kernel(const float* __restrict__ avg,
                            const float* __restrict__ W,
                            float* __restrict__ convout) {
    __shared__ float wlds[C_OUT * C_IN * 27];
    for (int t = threadIdx.x; t < C_OUT * C_IN * 27; t += blockDim.x)
        wlds[t] = W[t];
    __syncthreads();

    int cell = blockIdx.x * blockDim.x + threadIdx.x;
    if (cell >= NCELL) return;
    int z = cell & 31;
    int y = (cell >> 5) & 31;
    int x = cell >> 10;

    float acc[C_OUT];
#pragma unroll
    for (int c = 0; c < C_OUT; ++c) acc[c] = 0.f;

    for (int kd = 0; kd < 3; ++kd) {
        int nx = x + kd - 1;
        if (nx < 0 || nx >= G) continue;
        for (int kh = 0; kh < 3; ++kh) {
            int ny = y + kh - 1;
            if (ny < 0 || ny >= G) continue;
            for (int kw = 0; kw < 3; ++kw) {
                int nz = z + kw - 1;
                if (nz < 0 || nz >= G) continue;
                int nc = (nx * G + ny) * G + nz;
                float g0 = avg[nc * 3 + 0];
                float g1 = avg[nc * 3 + 1];
                float g2 = avg[nc * 3 + 2];
                int koff = (kd * 3 + kh) * 3 + kw;
#pragma unroll
                for (int co = 0; co < C_OUT; ++co) {
                    const float* wp = &wlds[co * C_IN * 27 + koff];
                    acc[co] += wp[0] * g0 + wp[27] * g1 + wp[54] * g2;
                }
            }
        }
    }
    float* op = &convout[(size_t)cell * C_OUT];
#pragma unroll
    for (int co = 0; co < C_OUT; ++co) op[co] = acc[co];
}

__global__ void gather_coords_kernel(const int* __restrict__ coords,
                                     const f32x4* __restrict__ convout,
                                     f32x4* __restrict__ out, int n) {
    long g = (long)blockIdx.x * blockDim.x + threadIdx.x;
    int i = (int)(g >> 4);
    int c4 = (int)(g & 15);
    if (i >= n) return;
    int x = coords[i * 3 + 0] >> 4;
    int y = coords[i * 3 + 1] >> 4;
    int z = coords[i * 3 + 2] >> 4;
    int cell = (x * G + y) * G + z;
    out[(size_t)i * 16 + c4] = convout[(size_t)cell * 16 + c4];
}

extern "C" void kernel_launch(void* const* d_in, const int* in_sizes, int n_in,
                              void* d_out, int out_size, void* d_ws, size_t ws_size,
                              hipStream_t stream) {
    const int*   coords = (const int*)d_in[0];
    const float* feats  = (const float*)d_in[1];
    const float* W      = (const float*)d_in[2];
    float* out = (float*)d_out;
    int n = in_sizes[0] / 3;   // 2,000,000

    float*          sums    = (float*)d_ws;
    float*          cnt     = sums + NCELL * 3;
    float*          avg     = cnt + NCELL;
    float*          convout = avg + NCELL * 3;                 // f32 table (fallback)
    _Float16*       tabA    = (_Float16*)(convout + (size_t)NCELL * 64);
    _Float16*       tabB    = tabA + (size_t)NCELL * 32;
    unsigned short* cellid  = (unsigned short*)((float*)tabA + (size_t)NCELL * 32);
    size_t          cid_elems = ((size_t)n + 7) & ~(size_t)7;  // keep 16B align
    float*          partial = (float*)(cellid + cid_elems);

    size_t need = ((size_t)NCELL * (3 + 1 + 3 + 64 + 32) +
                   (size_t)4 * PBLK * NCELL) * 4 + cid_elems * 2;
    bool fast = (ws_size >= need);

    if (fast) {
        int npt4 = (n + 3) / 4;
        cellid_kernel<<<(npt4 + 255) / 256, 256, 0, stream>>>(
            (const i32x4*)coords, cellid, n);
        int ppc = (n + PBLK - 1) / PBLK;
        histo_kernel<<<4 * PBLK, HTHREADS, 0, stream>>>(cellid, feats, partial, n, ppc);
        reduce_kernel<<<NCELL / 256, 256, 0, stream>>>(partial, avg);
        conv_half_kernel<<<NCELL / 256, 256, 0, stream>>>(avg, W, tabA, tabB);
        long ghalf = (long)n * 8;
        gather_half2_kernel<<<(int)((ghalf + 255) / 256), 256, 0, stream>>>(
            cellid, (const f16x4v*)tabA, (f32x4*)out, n, 0);
        gather_half2_kernel<<<(int)((ghalf + 255) / 256), 256, 0, stream>>>(
            cellid, (const f16x4v*)tabB, (f32x4*)out, n, 8);
    } else {
        hipMemsetAsync(d_ws, 0, NCELL * 4 * sizeof(float), stream);
        scatter_atomic_kernel<<<(n + 255) / 256, 256, 0, stream>>>(coords, feats, sums, cnt, n);
        avg_kernel<<<NCELL / 256, 256, 0, stream>>>(sums, cnt, avg);
        conv_kernel<<<NCELL / 256, 256, 0, stream>>>(avg, W, convout);
        long total = (long)n * 16;
        gather_coords_kernel<<<(int)((total + 255) / 256), 256, 0, stream>>>(
            coords, (const f32x4*)convout, (f32x4*)out, n);
    }
}